// Round 4
// baseline (1134.496 us; speedup 1.0000x reference)
//
#include <hip/hip_runtime.h>

#define B_   16
#define C_   32
#define O_   32
#define HW_  256
#define E_   4
#define HID_ 8
#define TEMP_ 30.0f
#define TSX 32
#define TSY 16

// ---------------- GAP: one block per (b,c) plane ----------------
__global__ __launch_bounds__(256) void gap_kernel(const float* __restrict__ x,
                                                  float* __restrict__ gap) {
    int bc = blockIdx.x;                      // b*32 + c
    const float4* p = (const float4*)(x + (size_t)bc * (HW_ * HW_));
    int t = threadIdx.x;
    float s = 0.f;
#pragma unroll 4
    for (int it = 0; it < 64; ++it) {         // 64*256 float4 = 65536 floats
        float4 v = p[it * 256 + t];
        s += v.x + v.y + v.z + v.w;
    }
    __shared__ float red[256];
    red[t] = s;
    __syncthreads();
    for (int off = 128; off > 0; off >>= 1) {
        if (t < off) red[t] += red[t + off];
        __syncthreads();
    }
    if (t == 0) gap[bc] = red[0] * (1.f / (HW_ * HW_));
}

// ------------- control MLP + softmax + weight assembly -------------
// grid: (16 samples, 3 tensors); 256 threads
__global__ __launch_bounds__(256) void assemble_kernel(
    const float* __restrict__ gap,
    const float* __restrict__ w_c1,   // [8][32]
    const float* __restrict__ w_c2,   // [128][8]
    const float* __restrict__ wt1,    // [4][32][32*9]
    const float* __restrict__ wt2,
    const float* __restrict__ wt3,
    float* __restrict__ wo1,          // [16][32][32*9]
    float* __restrict__ wo2,
    float* __restrict__ wo3)
{
    int b = blockIdx.x;
    int sel = blockIdx.y;
    int t = threadIdx.x;
    __shared__ float gap_s[32], h_s[8], logit_s[128], coeff_s[32][4];
    if (t < 32) gap_s[t] = gap[b * 32 + t];
    __syncthreads();
    if (t < HID_) {
        float a = 0.f;
        for (int c = 0; c < 32; ++c) a += gap_s[c] * w_c1[t * 32 + c];
        h_s[t] = a > 0.f ? a : 0.f;
    }
    __syncthreads();
    if (t < 128) {
        float a = 0.f;
        for (int k = 0; k < HID_; ++k) a += h_s[k] * w_c2[t * HID_ + k];
        logit_s[t] = a * (1.0f / TEMP_);
    }
    __syncthreads();
    if (t < 32) {
        float m = -1e30f;
        for (int e = 0; e < 4; ++e) m = fmaxf(m, logit_s[t * 4 + e]);
        float ex[4], sum = 0.f;
        for (int e = 0; e < 4; ++e) { ex[e] = expf(logit_s[t * 4 + e] - m); sum += ex[e]; }
        for (int e = 0; e < 4; ++e) coeff_s[t][e] = ex[e] / sum;
    }
    __syncthreads();

    const float* wt = sel == 0 ? wt1 : (sel == 1 ? wt2 : wt3);
    float* wo = sel == 0 ? wo1 : (sel == 1 ? wo2 : wo3);

    for (int o = 0; o < 32; ++o) {
        float c0 = coeff_s[o][0], c1 = coeff_s[o][1], c2 = coeff_s[o][2], c3 = coeff_s[o][3];
        for (int j = t; j < 288; j += 256) {
            float v = c0 * wt[(0 * 32 + o) * 288 + j]
                    + c1 * wt[(1 * 32 + o) * 288 + j]
                    + c2 * wt[(2 * 32 + o) * 288 + j]
                    + c3 * wt[(3 * 32 + o) * 288 + j];
            wo[((size_t)b * 32 + o) * 288 + j] = v;
        }
    }
}

// ------------- 3x3 conv, per-sample weights -------------
// grid: (256/TSX, 256/TSY, 16); 256 threads (4 waves)
// wave w owns output channels [8w, 8w+8); thread: 2 rows x 4 px x 8 O
__global__ __launch_bounds__(256, 2) void conv3x3_kernel(
    const float* __restrict__ src,    // [16][32][256][256]
    const float* __restrict__ wgt,    // [16][32][32*9]
    float* __restrict__ dst)          // [16][32][256][256]
{
    __shared__ float lds[C_][TSY + 2][TSX + 3];   // pad 34->35: 2-way max alias
    int b   = blockIdx.z;
    int tx0 = blockIdx.x * TSX;
    int ty0 = blockIdx.y * TSY;
    int t   = threadIdx.x;

    // stage (TSY+2)x(TSX+2)x32 input tile, zero-padded at borders
    const float* sb = src + (size_t)b * C_ * HW_ * HW_;
    const int NSTG = C_ * (TSY + 2) * (TSX + 2);   // 19584
    for (int idx = t; idx < NSTG; idx += 256) {
        int c = idx / ((TSY + 2) * (TSX + 2));
        int rem = idx % ((TSY + 2) * (TSX + 2));
        int r = rem / (TSX + 2);
        int col = rem % (TSX + 2);
        int gy = ty0 - 1 + r;
        int gx = tx0 - 1 + col;
        float v = 0.f;
        if ((unsigned)gy < HW_ && (unsigned)gx < HW_)
            v = sb[((size_t)c * HW_ + gy) * HW_ + gx];
        lds[c][r][col] = v;
    }
    __syncthreads();

    int lane  = t & 63;
    int wave  = __builtin_amdgcn_readfirstlane(t >> 6);
    int obase = wave * 8;
    int pxg   = lane & 7;      // columns pxg*4 .. pxg*4+3
    int py    = lane >> 3;     // rows py and py+8
    const float* wb = wgt + ((size_t)b * O_ + obase) * (C_ * 9);

    float acc[2][8][4];
#pragma unroll
    for (int r = 0; r < 2; ++r)
#pragma unroll
        for (int o = 0; o < 8; ++o)
#pragma unroll
            for (int i = 0; i < 4; ++i) acc[r][o][i] = 0.f;

    for (int c = 0; c < C_; ++c) {
#pragma unroll
        for (int dy = 0; dy < 3; ++dy) {
            float v0[6], v1[6];
#pragma unroll
            for (int i = 0; i < 6; ++i) {
                v0[i] = lds[c][py + dy][pxg * 4 + i];
                v1[i] = lds[c][py + 8 + dy][pxg * 4 + i];
            }
#pragma unroll
            for (int dx = 0; dx < 3; ++dx) {
#pragma unroll
                for (int o = 0; o < 8; ++o) {
                    float w = wb[(o * C_ + c) * 9 + dy * 3 + dx];  // wave-uniform -> s_load
#pragma unroll
                    for (int i = 0; i < 4; ++i) {
                        acc[0][o][i] = fmaf(v0[i + dx], w, acc[0][o][i]);
                        acc[1][o][i] = fmaf(v1[i + dx], w, acc[1][o][i]);
                    }
                }
            }
        }
    }

    float* db = dst + (size_t)b * O_ * HW_ * HW_;
#pragma unroll
    for (int r = 0; r < 2; ++r) {
        int gy = ty0 + py + r * 8;
#pragma unroll
        for (int o = 0; o < 8; ++o) {
            float4 v = make_float4(acc[r][o][0], acc[r][o][1], acc[r][o][2], acc[r][o][3]);
            *(float4*)(db + ((size_t)(obase + o) * HW_ + gy) * HW_ + tx0 + pxg * 4) = v;
        }
    }
}

extern "C" void kernel_launch(void* const* d_in, const int* in_sizes, int n_in,
                              void* d_out, int out_size, void* d_ws, size_t ws_size,
                              hipStream_t stream) {
    const float* x    = (const float*)d_in[0];
    const float* w_c1 = (const float*)d_in[1];
    const float* w_c2 = (const float*)d_in[2];
    const float* wt1  = (const float*)d_in[3];
    const float* wt2  = (const float*)d_in[4];
    const float* wt3  = (const float*)d_in[5];
    float* out = (float*)d_out;

    char* ws = (char*)d_ws;
    float* gap = (float*)ws;                              // 512 floats
    float* w1  = (float*)(ws + 2048);                     // 147456 floats each
    float* w2  = w1 + 147456;
    float* w3  = w2 + 147456;
    float* t2  = (float*)(ws + 1771520);                  // 33554432 floats

    gap_kernel<<<512, 256, 0, stream>>>(x, gap);
    assemble_kernel<<<dim3(16, 3), 256, 0, stream>>>(gap, w_c1, w_c2,
                                                     wt1, wt2, wt3, w1, w2, w3);
    dim3 cgrid(HW_ / TSX, HW_ / TSY, B_);
    conv3x3_kernel<<<cgrid, 256, 0, stream>>>(x,   w1, out);   // conv1: x -> out
    conv3x3_kernel<<<cgrid, 256, 0, stream>>>(out, w2, t2);    // conv2: out -> t2
    conv3x3_kernel<<<cgrid, 256, 0, stream>>>(t2,  w3, out);   // conv3: t2 -> out
}

// Round 6
// 409.408 us; speedup vs baseline: 2.7711x; 2.7711x over previous
//
#include <hip/hip_runtime.h>

typedef __attribute__((ext_vector_type(8))) short bf16x8;
typedef __attribute__((ext_vector_type(4))) float f32x4;

#define B_   16
#define HW_  256
#define HID_ 8
#define TEMP_ 30.0f

static __device__ inline unsigned short f2bf(float f) {
    unsigned u = __builtin_bit_cast(unsigned, f);
    u = (u + 0x7FFFu + ((u >> 16) & 1u)) >> 16;   // RNE
    return (unsigned short)u;
}
static __device__ inline unsigned packbf(float a, float b) {
    return (unsigned)f2bf(a) | ((unsigned)f2bf(b) << 16);
}

// ---------------- GAP: 2048 blocks, quarter-plane each, atomicAdd ----------------
__global__ __launch_bounds__(256) void gap_kernel(const float* __restrict__ x,
                                                  float* __restrict__ gap) {
    int blk = blockIdx.x;
    int bc = blk >> 2, q = blk & 3;               // bc = b*32+c
    const float4* p = (const float4*)(x + ((size_t)bc << 16)) + q * 4096;
    int t = threadIdx.x;
    float s = 0.f;
#pragma unroll
    for (int i = 0; i < 16; ++i) {
        float4 v = p[i * 256 + t];
        s += v.x + v.y + v.z + v.w;
    }
    __shared__ float red[256];
    red[t] = s;
    __syncthreads();
    for (int off = 128; off > 0; off >>= 1) {
        if (t < off) red[t] += red[t + off];
        __syncthreads();
    }
    if (t == 0) atomicAdd(&gap[bc], red[0] * (1.f / 65536.f));
}

// ------- control MLP + softmax + blended weights -> bf16 [b][9][o(32)][c(32)] -------
__global__ __launch_bounds__(256) void assemble_kernel(
    const float* __restrict__ gap,
    const float* __restrict__ w_c1,   // [8][32]
    const float* __restrict__ w_c2,   // [128][8]
    const float* __restrict__ wt1,    // [4][32][288], inner j = c*9 + dy*3+dx
    const float* __restrict__ wt2,
    const float* __restrict__ wt3,
    unsigned short* __restrict__ wo1, // [16][9][32][32] bf16
    unsigned short* __restrict__ wo2,
    unsigned short* __restrict__ wo3)
{
    int b = blockIdx.x;
    int sel = blockIdx.y;
    int t = threadIdx.x;
    __shared__ float gap_s[32], h_s[8], logit_s[128], coeff_s[32][4];
    if (t < 32) gap_s[t] = gap[b * 32 + t];
    __syncthreads();
    if (t < HID_) {
        float a = 0.f;
        for (int c = 0; c < 32; ++c) a += gap_s[c] * w_c1[t * 32 + c];
        h_s[t] = a > 0.f ? a : 0.f;
    }
    __syncthreads();
    if (t < 128) {
        float a = 0.f;
        for (int k = 0; k < HID_; ++k) a += h_s[k] * w_c2[t * HID_ + k];
        logit_s[t] = a * (1.0f / TEMP_);
    }
    __syncthreads();
    if (t < 32) {
        float m = -1e30f;
        for (int e = 0; e < 4; ++e) m = fmaxf(m, logit_s[t * 4 + e]);
        float ex[4], sum = 0.f;
        for (int e = 0; e < 4; ++e) { ex[e] = expf(logit_s[t * 4 + e] - m); sum += ex[e]; }
        for (int e = 0; e < 4; ++e) coeff_s[t][e] = ex[e] / sum;
    }
    __syncthreads();

    const float* wt = sel == 0 ? wt1 : (sel == 1 ? wt2 : wt3);
    unsigned short* wo = sel == 0 ? wo1 : (sel == 1 ? wo2 : wo3);

    for (int idx = t; idx < 9216; idx += 256) {   // idx = d*1024 + o*32 + c
        int d = idx >> 10;
        int o = (idx >> 5) & 31;
        int c = idx & 31;
        int j = c * 9 + d;
        float v = coeff_s[o][0] * wt[(0 * 32 + o) * 288 + j]
                + coeff_s[o][1] * wt[(1 * 32 + o) * 288 + j]
                + coeff_s[o][2] * wt[(2 * 32 + o) * 288 + j]
                + coeff_s[o][3] * wt[(3 * 32 + o) * 288 + j];
        wo[(size_t)b * 9216 + idx] = f2bf(v);
    }
}

// ------------- 3x3 conv via MFMA implicit GEMM -------------
// tile: 32x16 output px, all 32 O. LDS: input tile 34x18 px, HWC bf16 (c contiguous).
// grid (8,16,16), 256 thr = 4 waves. Wave w: rows [4w,4w+4), both 16-px x-halves.
// per 16px-tile: 9 ds_read_b128 (B-frags) + 18 mfma_16x16x32 (2 o-blocks).
// IN_F32: src = fp32 NCHW (gather 8 planes, cvt bf16). else bf16 NHWC (uint4 copy).
// OUT_F32: dst = fp32 NCHW (d_out). else bf16 NHWC.
template<int IN_F32, int OUT_F32>
__global__ __launch_bounds__(256) void conv3x3_mfma(
    const void* __restrict__ src,
    const unsigned short* __restrict__ wgt,   // [16][9][32][32] bf16
    void* __restrict__ dst)
{
    __shared__ uint4 lds[2448];                // 612 px * 64B = 39168 B
    int b  = blockIdx.z;
    int x0 = blockIdx.x * 32, y0 = blockIdx.y * 16;
    int t  = threadIdx.x;
    int l15 = t & 15;
    int kg  = (t >> 4) & 3;                    // lane>>4
    int wv  = t >> 6;

    // ---- A-frags: W[d][oblk]: lane holds W[o = ob*16 + l15][c = kg*8 .. +8)
    bf16x8 wf[9][2];
    {
        const uint4* wp = (const uint4*)(wgt + (size_t)b * 9216);
#pragma unroll
        for (int d = 0; d < 9; ++d)
#pragma unroll
            for (int ob = 0; ob < 2; ++ob)
                wf[d][ob] = __builtin_bit_cast(bf16x8, wp[(d * 32 + ob * 16 + l15) * 4 + kg]);
    }

    // ---- stage input tile -> LDS [y(18)][x(34)][c(32)] bf16; task = (px, cgroup8)
#pragma unroll
    for (int it = 0; it < 10; ++it) {
        int tau = it * 256 + t;
        if (tau < 2448) {
            int px = tau >> 2, cg = tau & 3;
            int yy = px / 34;
            int xx = px - yy * 34;
            int gy = y0 - 1 + yy, gx = x0 - 1 + xx;
            uint4 v = make_uint4(0u, 0u, 0u, 0u);
            if ((unsigned)gy < 256u && (unsigned)gx < 256u) {
                if (IN_F32) {
                    const float* sp = (const float*)src
                        + (((size_t)b * 32 + cg * 8) << 16) + (gy << 8) + gx;
                    float f0 = sp[0],         f1 = sp[1 << 16];
                    float f2 = sp[2 << 16],   f3 = sp[3 << 16];
                    float f4 = sp[4 << 16],   f5 = sp[5 << 16];
                    float f6 = sp[6 << 16],   f7 = sp[7 << 16];
                    v.x = packbf(f0, f1); v.y = packbf(f2, f3);
                    v.z = packbf(f4, f5); v.w = packbf(f6, f7);
                } else {
                    v = *((const uint4*)src
                          + (((size_t)b << 16) + (gy << 8) + gx) * 4 + cg);
                }
            }
            lds[tau] = v;
        }
    }
    __syncthreads();

    // ---- compute: 8 px-tiles per wave
    const bf16x8* lp = (const bf16x8*)lds;     // 16B units
#pragma unroll
    for (int r = 0; r < 4; ++r) {
        int yl = wv * 4 + r;
#pragma unroll
        for (int xt = 0; xt < 2; ++xt) {
            int base = (yl * 34 + xt * 16 + l15) * 4 + kg;
            f32x4 a0 = {0.f, 0.f, 0.f, 0.f};
            f32x4 a1 = {0.f, 0.f, 0.f, 0.f};
#pragma unroll
            for (int d = 0; d < 9; ++d) {
                bf16x8 bfr = lp[base + ((d / 3) * 34 + (d % 3)) * 4];
                a0 = __builtin_amdgcn_mfma_f32_16x16x32_bf16(wf[d][0], bfr, a0, 0, 0, 0);
                a1 = __builtin_amdgcn_mfma_f32_16x16x32_bf16(wf[d][1], bfr, a1, 0, 0, 0);
            }
            int gy = y0 + yl, gx = x0 + xt * 16 + l15;
            if (OUT_F32) {
                float* dp = (float*)dst + (((size_t)b * 32 + kg * 4) << 16) + (gy << 8) + gx;
#pragma unroll
                for (int r2 = 0; r2 < 4; ++r2) {
                    dp[(size_t)r2 << 16]        = a0[r2];
                    dp[(size_t)(r2 + 16) << 16] = a1[r2];
                }
            } else {
                unsigned short* dp = (unsigned short*)dst
                    + ((((size_t)b << 16) + (gy << 8) + gx) * 32) + kg * 4;
                uint2 p0, p1;
                p0.x = packbf(a0[0], a0[1]); p0.y = packbf(a0[2], a0[3]);
                p1.x = packbf(a1[0], a1[1]); p1.y = packbf(a1[2], a1[3]);
                *(uint2*)dp        = p0;
                *(uint2*)(dp + 16) = p1;
            }
        }
    }
}

extern "C" void kernel_launch(void* const* d_in, const int* in_sizes, int n_in,
                              void* d_out, int out_size, void* d_ws, size_t ws_size,
                              hipStream_t stream) {
    const float* x    = (const float*)d_in[0];
    const float* w_c1 = (const float*)d_in[1];
    const float* w_c2 = (const float*)d_in[2];
    const float* wt1  = (const float*)d_in[3];
    const float* wt2  = (const float*)d_in[4];
    const float* wt3  = (const float*)d_in[5];
    float* out = (float*)d_out;

    char* ws = (char*)d_ws;
    float* gap = (float*)ws;                                    // 512 f
    unsigned short* w1 = (unsigned short*)(ws + 2048);          // 147456 ushort each
    unsigned short* w2 = w1 + 147456;
    unsigned short* w3 = w2 + 147456;
    unsigned short* t1 = (unsigned short*)(ws + 983040);        // 67108864 B
    unsigned short* t2 = (unsigned short*)(ws + 983040 + 67108864);
    // total ws use: 983040 + 134217728 = 135200768 B

    hipMemsetAsync(gap, 0, 2048, stream);                       // capture-safe
    gap_kernel<<<2048, 256, 0, stream>>>(x, gap);
    assemble_kernel<<<dim3(16, 3), 256, 0, stream>>>(gap, w_c1, w_c2,
                                                     wt1, wt2, wt3, w1, w2, w3);
    dim3 cg(8, 16, B_);
    conv3x3_mfma<1, 0><<<cg, 256, 0, stream>>>(x,  w1, t1);     // fp32 NCHW -> bf16 NHWC
    conv3x3_mfma<0, 0><<<cg, 256, 0, stream>>>(t1, w2, t2);     // bf16 NHWC -> bf16 NHWC
    conv3x3_mfma<0, 1><<<cg, 256, 0, stream>>>(t2, w3, out);    // bf16 NHWC -> fp32 NCHW
}

// Round 8
// 389.137 us; speedup vs baseline: 2.9154x; 1.0521x over previous
//
#include <hip/hip_runtime.h>

typedef __attribute__((ext_vector_type(8))) short bf16x8;
typedef __attribute__((ext_vector_type(4))) float f32x4;

#define TEMP_ 30.0f
#define MFMA(A,B,C) __builtin_amdgcn_mfma_f32_16x16x32_bf16(A,B,C,0,0,0)

static __device__ inline unsigned short f2bf(float f) {
    unsigned u = __builtin_bit_cast(unsigned, f);
    u = (u + 0x7FFFu + ((u >> 16) & 1u)) >> 16;   // RNE
    return (unsigned short)u;
}
static __device__ inline unsigned packbf(float a, float b) {
    return (unsigned)f2bf(a) | ((unsigned)f2bf(b) << 16);
}
static __device__ inline bf16x8 bc16(uint4 v) { return __builtin_bit_cast(bf16x8, v); }

// ---------- kernel 1: GAP + fp32 NCHW -> bf16 NHWC transpose ----------
// grid (64, 16): 4-row slab per (b); 256 thr (4 waves = 4 rows)
__global__ __launch_bounds__(256) void gap_cvt_kernel(
    const float* __restrict__ x, float* __restrict__ gap,
    unsigned short* __restrict__ xbf)        // [16][256][256][32] bf16
{
    __shared__ unsigned short sm[32 * 4 * 258];   // [c][y4][x pad->258]
    __shared__ float red[4][32];
    int b = blockIdx.y, ys = blockIdx.x * 4;
    int t = threadIdx.x, wv = t >> 6, ln = t & 63;

    const float* xb = x + (((size_t)b * 32) << 16) + ((size_t)(ys + wv) << 8) + ln * 4;
    float part[32];
#pragma unroll
    for (int c = 0; c < 32; ++c) {
        float4 v = *(const float4*)(xb + ((size_t)c << 16));
        part[c] = v.x + v.y + v.z + v.w;
        unsigned* wp = (unsigned*)&sm[c * 1032 + wv * 258 + ln * 4];
        wp[0] = packbf(v.x, v.y);
        wp[1] = packbf(v.z, v.w);
    }
#pragma unroll
    for (int c = 0; c < 32; ++c) {
#pragma unroll
        for (int off = 32; off; off >>= 1) part[c] += __shfl_xor(part[c], off);
    }
    if (ln == 0) {
#pragma unroll
        for (int c = 0; c < 32; ++c) red[wv][c] = part[c];
    }
    __syncthreads();
    if (t < 32) {
        float s = red[0][t] + red[1][t] + red[2][t] + red[3][t];
        atomicAdd(&gap[b * 32 + t], s * (1.f / 65536.f));
    }
    // phase B: write NHWC bf16. wave wv handles c-group wv; lanes = 64 consecutive x.
    uint4* outp = (uint4*)xbf;
    int cg = wv;
#pragma unroll
    for (int it = 0; it < 16; ++it) {
        int px = it * 64 + ln;                 // 0..1023 within slab
        int y = px >> 8, xx = px & 255;
        unsigned short h[8];
#pragma unroll
        for (int i = 0; i < 8; ++i) h[i] = sm[(cg * 8 + i) * 1032 + y * 258 + xx];
        uint4 v;
        v.x = (unsigned)h[0] | ((unsigned)h[1] << 16);
        v.y = (unsigned)h[2] | ((unsigned)h[3] << 16);
        v.z = (unsigned)h[4] | ((unsigned)h[5] << 16);
        v.w = (unsigned)h[6] | ((unsigned)h[7] << 16);
        outp[((((size_t)b << 16) + ((size_t)(ys + y) << 8) + xx) << 2) + cg] = v;
    }
}

// ------- control MLP + softmax + blended weights -> bf16 [b][9][o(32)][c(32)] -------
__global__ __launch_bounds__(256) void assemble_kernel(
    const float* __restrict__ gap,
    const float* __restrict__ w_c1,   // [8][32]
    const float* __restrict__ w_c2,   // [128][8]
    const float* __restrict__ wt1,    // [4][32][288], inner j = c*9 + dy*3+dx
    const float* __restrict__ wt2,
    const float* __restrict__ wt3,
    unsigned short* __restrict__ wo1,
    unsigned short* __restrict__ wo2,
    unsigned short* __restrict__ wo3)
{
    int b = blockIdx.x;
    int sel = blockIdx.y;
    int t = threadIdx.x;
    __shared__ float gap_s[32], h_s[8], logit_s[128], coeff_s[32][4];
    if (t < 32) gap_s[t] = gap[b * 32 + t];
    __syncthreads();
    if (t < 8) {
        float a = 0.f;
        for (int c = 0; c < 32; ++c) a += gap_s[c] * w_c1[t * 32 + c];
        h_s[t] = a > 0.f ? a : 0.f;
    }
    __syncthreads();
    if (t < 128) {
        float a = 0.f;
        for (int k = 0; k < 8; ++k) a += h_s[k] * w_c2[t * 8 + k];
        logit_s[t] = a * (1.0f / TEMP_);
    }
    __syncthreads();
    if (t < 32) {
        float m = -1e30f;
        for (int e = 0; e < 4; ++e) m = fmaxf(m, logit_s[t * 4 + e]);
        float ex[4], sum = 0.f;
        for (int e = 0; e < 4; ++e) { ex[e] = expf(logit_s[t * 4 + e] - m); sum += ex[e]; }
        for (int e = 0; e < 4; ++e) coeff_s[t][e] = ex[e] / sum;
    }
    __syncthreads();

    const float* wt = sel == 0 ? wt1 : (sel == 1 ? wt2 : wt3);
    unsigned short* wo = sel == 0 ? wo1 : (sel == 1 ? wo2 : wo3);

    for (int idx = t; idx < 9216; idx += 256) {   // idx = d*1024 + o*32 + c
        int d = idx >> 10;
        int o = (idx >> 5) & 31;
        int c = idx & 31;
        int j = c * 9 + d;
        float v = coeff_s[o][0] * wt[(0 * 32 + o) * 288 + j]
                + coeff_s[o][1] * wt[(1 * 32 + o) * 288 + j]
                + coeff_s[o][2] * wt[(2 * 32 + o) * 288 + j]
                + coeff_s[o][3] * wt[(3 * 32 + o) * 288 + j];
        wo[(size_t)b * 9216 + idx] = f2bf(v);
    }
}

// ------------- fused conv1->conv2->conv3, all intermediates in LDS -------------
// final tile 32x16. regions: in 38x22 (bufA), c1out 48x20 wide-padded (buf1, X'<36
// valid), c2out 34x18 (aliases bufA), out 32x16 -> global fp32 NCHW.
// Chained pad=1: intermediate values at global coords outside [0,256)^2 are ZEROED.
// grid (8,16,16), 512 thr (8 waves), LDS 115 KB -> 1 block/CU, 2 waves/SIMD.
__global__ __launch_bounds__(512, 2) void fused_conv3(
    const unsigned short* __restrict__ xbf,   // [16][256][256][32]
    const unsigned short* __restrict__ w1,    // [16][9][32][32]
    const unsigned short* __restrict__ w2,
    const unsigned short* __restrict__ w3,
    float* __restrict__ out)                  // [16][32][256][256]
{
    __shared__ uint4 lds[7192];   // [0,3344) bufA; [3344,7184) buf1; 8 pad
    int b  = blockIdx.z;
    int x0 = blockIdx.x * 32, y0 = blockIdx.y * 16;
    int t  = threadIdx.x;
    int l15 = t & 15, kg = (t >> 4) & 3, wv = t >> 6;

    const uint4* wp1 = (const uint4*)(w1 + (size_t)b * 9216);
    const uint4* wp2 = (const uint4*)(w2 + (size_t)b * 9216);
    const uint4* wp3 = (const uint4*)(w3 + (size_t)b * 9216);

    bf16x8 wfA[9][2], wfB[9][2];
#pragma unroll
    for (int d = 0; d < 9; ++d) {              // conv1 weights (issue early)
        wfA[d][0] = bc16(wp1[(d * 32 + l15) * 4 + kg]);
        wfA[d][1] = bc16(wp1[(d * 32 + 16 + l15) * 4 + kg]);
    }

    // stage 38x22 bf16 HWC tile into bufA (3344 uint4 tasks)
    const unsigned short* xb = xbf + (((size_t)b) << 16) * 32;
    for (int it = 0; it < 7; ++it) {
        int tau = it * 512 + t;
        if (tau < 3344) {
            int y = tau / 152, rem = tau - y * 152;
            int xx = rem >> 2, cg = rem & 3;
            int gy = y0 - 3 + y, gx = x0 - 3 + xx;
            uint4 v = make_uint4(0u, 0u, 0u, 0u);
            if ((unsigned)gy < 256u && (unsigned)gx < 256u)
                v = *(const uint4*)(xb + ((((size_t)gy << 8) + gx) << 5) + (cg << 3));
            lds[tau] = v;
        }
    }
#pragma unroll
    for (int d = 0; d < 9; ++d) {              // conv2 weights prefetch
        wfB[d][0] = bc16(wp2[(d * 32 + l15) * 4 + kg]);
        wfB[d][1] = bc16(wp2[(d * 32 + 16 + l15) * 4 + kg]);
    }
    __syncthreads();

    const bf16x8* LA = (const bf16x8*)lds;            // 16B-unit views
    const bf16x8* L1 = (const bf16x8*)(lds + 3344);
    unsigned short* SA = (unsigned short*)lds;
    unsigned short* S1 = (unsigned short*)(lds + 3344);

    // ---- conv1: 20 rows x 3 xtiles (48 wide; X'<36 real) ----
    for (int i = wv; i < 60; i += 8) {
        int row = i / 3, xt = i - row * 3;
        int Xp = xt * 16 + l15;
        int base = (row * 38 + Xp) * 4 + kg;
        f32x4 a0 = {0.f,0.f,0.f,0.f}, a1 = {0.f,0.f,0.f,0.f};
#pragma unroll
        for (int d = 0; d < 9; ++d) {
            bf16x8 bfr = LA[base + (d / 3) * 152 + (d % 3) * 4];
            a0 = MFMA(wfA[d][0], bfr, a0);
            a1 = MFMA(wfA[d][1], bfr, a1);
        }
        bool live = ((unsigned)(y0 - 2 + row) < 256u) && ((unsigned)(x0 - 2 + Xp) < 256u);
        uint2 p0, p1;
        p0.x = packbf(a0[0], a0[1]); p0.y = packbf(a0[2], a0[3]);
        p1.x = packbf(a1[0], a1[1]); p1.y = packbf(a1[2], a1[3]);
        if (!live) { p0.x = p0.y = p1.x = p1.y = 0u; }   // zero outside true domain
        unsigned short* dp = S1 + ((row * 48 + Xp) << 5);
        *(uint2*)(dp + (kg << 2))      = p0;   // ch o = kg*4..+3
        *(uint2*)(dp + 16 + (kg << 2)) = p1;   // ch o = 16+kg*4..+3  (FIX: was +32)
    }
#pragma unroll
    for (int d = 0; d < 9; ++d) {              // conv3 weights prefetch (reuse wfA)
        wfA[d][0] = bc16(wp3[(d * 32 + l15) * 4 + kg]);
        wfA[d][1] = bc16(wp3[(d * 32 + 16 + l15) * 4 + kg]);
    }
    __syncthreads();

    // ---- conv2: 18 rows x 3 xtiles (X''<34 real) -> buf2 (aliases bufA) ----
    for (int i = wv; i < 54; i += 8) {
        int row = i / 3, xt = i - row * 3;
        int Xp = xt * 16 + l15;
        int base = (row * 48 + Xp) * 4 + kg;
        f32x4 a0 = {0.f,0.f,0.f,0.f}, a1 = {0.f,0.f,0.f,0.f};
#pragma unroll
        for (int d = 0; d < 9; ++d) {
            bf16x8 bfr = L1[base + (d / 3) * 192 + (d % 3) * 4];
            a0 = MFMA(wfB[d][0], bfr, a0);
            a1 = MFMA(wfB[d][1], bfr, a1);
        }
        if (Xp < 34) {
            bool live = ((unsigned)(y0 - 1 + row) < 256u) && ((unsigned)(x0 - 1 + Xp) < 256u);
            uint2 p0, p1;
            p0.x = packbf(a0[0], a0[1]); p0.y = packbf(a0[2], a0[3]);
            p1.x = packbf(a1[0], a1[1]); p1.y = packbf(a1[2], a1[3]);
            if (!live) { p0.x = p0.y = p1.x = p1.y = 0u; }
            unsigned short* dp = SA + ((row * 34 + Xp) << 5);
            *(uint2*)(dp + (kg << 2))      = p0;
            *(uint2*)(dp + 16 + (kg << 2)) = p1;          // (FIX: was +32)
        }
    }
    __syncthreads();

    // ---- conv3: 16 rows x 2 xtiles -> global fp32 NCHW ----
    for (int i = wv; i < 32; i += 8) {
        int row = i >> 1, xt = i & 1;
        int Xp = xt * 16 + l15;
        int base = (row * 34 + Xp) * 4 + kg;
        f32x4 a0 = {0.f,0.f,0.f,0.f}, a1 = {0.f,0.f,0.f,0.f};
#pragma unroll
        for (int d = 0; d < 9; ++d) {
            bf16x8 bfr = LA[base + (d / 3) * 136 + (d % 3) * 4];
            a0 = MFMA(wfA[d][0], bfr, a0);
            a1 = MFMA(wfA[d][1], bfr, a1);
        }
        int gy = y0 + row, gx = x0 + Xp;
        float* dp = out + (((size_t)b * 32 + kg * 4) << 16) + ((size_t)gy << 8) + gx;
#pragma unroll
        for (int r2 = 0; r2 < 4; ++r2) {
            dp[(size_t)r2 << 16]        = a0[r2];
            dp[(size_t)(r2 + 16) << 16] = a1[r2];
        }
    }
}

extern "C" void kernel_launch(void* const* d_in, const int* in_sizes, int n_in,
                              void* d_out, int out_size, void* d_ws, size_t ws_size,
                              hipStream_t stream) {
    const float* x    = (const float*)d_in[0];
    const float* w_c1 = (const float*)d_in[1];
    const float* w_c2 = (const float*)d_in[2];
    const float* wt1  = (const float*)d_in[3];
    const float* wt2  = (const float*)d_in[4];
    const float* wt3  = (const float*)d_in[5];
    float* out = (float*)d_out;

    char* ws = (char*)d_ws;
    float* gap = (float*)ws;                                   // 512 f @0
    unsigned short* w1 = (unsigned short*)(ws + 4096);         // 294912 B each
    unsigned short* w2 = (unsigned short*)(ws + 4096 + 294912);
    unsigned short* w3 = (unsigned short*)(ws + 4096 + 2 * 294912);
    unsigned short* xbf = (unsigned short*)(ws + 1048576);     // 67108864 B

    hipMemsetAsync(gap, 0, 2048, stream);
    gap_cvt_kernel<<<dim3(64, 16), 256, 0, stream>>>(x, gap, xbf);
    assemble_kernel<<<dim3(16, 3), 256, 0, stream>>>(gap, w_c1, w_c2,
                                                     wt1, wt2, wt3, w1, w2, w3);
    fused_conv3<<<dim3(8, 16, 16), 512, 0, stream>>>(xbf, w1, w2, w3, out);
}